// Round 7
// baseline (2103.139 us; speedup 1.0000x reference)
//
#include <hip/hip_runtime.h>
#include <hip/hip_bf16.h>
#include <stdint.h>
#include <stddef.h>

// LSTM: T=512, B=64, I=512, H=512.
// Phase 1: xproj GEMM (bf16 MFMA), output re-laid as [t][j=32][row=64][g=4][c=16].
// Phase 2: 128 independent waves (32 col-groups x 4 row-groups), 64-thr WGs.
//          R7: TAG-IN-BAND handshake. h element = 32-bit word: bf16(h) | tag<<16,
//          tag = step that produced it. Producers fire-and-forget tagged stores
//          (sc0 sc1); consumers poll the data itself and AND-validate all 128
//          tags (stale tags are always < t, so AND's high half == t iff all
//          fresh). Removes producer drain + flag publish + flag-poll RT: ONE
//          LLC round trip per step on the critical path (was three).

#define T_STEPS 512
#define BATCH   64
#define HDIM    512

using short8 = __attribute__((ext_vector_type(8))) short;  // 8 bf16 (4 VGPR) MFMA operand
using f32x4  = __attribute__((ext_vector_type(4))) float;  // MFMA accumulator
using int4v  = __attribute__((ext_vector_type(4))) int;

__device__ __forceinline__ void gload_lds16(const void* g, void* l) {
  __builtin_amdgcn_global_load_lds((const __attribute__((address_space(1))) void*)g,
                                   (__attribute__((address_space(3))) void*)l, 16, 0, 0);
}
__device__ __forceinline__ float sigf(float x) { return 1.0f / (1.0f + __expf(-x)); }
__device__ __forceinline__ float tanh_fast(float x) {
  x = fminf(fmaxf(x, -15.0f), 15.0f);
  float e = __expf(2.0f * x);
  return (e - 1.0f) / (e + 1.0f);
}
__device__ __forceinline__ short bfb(float f) {
  __hip_bfloat16 h = __float2bfloat16(f);
  short s; __builtin_memcpy(&s, &h, 2); return s;
}
__device__ __forceinline__ unsigned bfbits(float f) {
  __hip_bfloat16 h = __float2bfloat16(f);
  unsigned short s; __builtin_memcpy(&s, &h, 2); return (unsigned)s;
}
__device__ __forceinline__ float bf2f(unsigned u) {  // bf16 bits (low 16) -> f32
  return __builtin_bit_cast(float, u << 16);
}

// ---------------- prep: build Wx_bt/Wh_bt [2048][512] bf16, bias[2048], zero hbuf32
__global__ __launch_bounds__(256) void k_prep(
    const float* __restrict__ Wf, const float* __restrict__ bf_,
    const float* __restrict__ Wi, const float* __restrict__ bi,
    const float* __restrict__ Wg, const float* __restrict__ bg,
    const float* __restrict__ Wo, const float* __restrict__ bo,
    __hip_bfloat16* __restrict__ wxbt, __hip_bfloat16* __restrict__ whbt,
    float* __restrict__ bias, unsigned* __restrict__ hbuf32)
{
  int idx = blockIdx.x * 256 + threadIdx.x;   // 4096 blocks -> 1,048,576 = 2048*512
  int row = idx >> 9;                          // 0..2047 (gate-major)
  int k   = idx & 511;
  int g = row >> 9, r = row & 511;
  const float* W = (g == 0) ? Wf : (g == 1) ? Wi : (g == 2) ? Wg : Wo;
  const float* B = (g == 0) ? bf_ : (g == 1) ? bi : (g == 2) ? bg : bo;
  wxbt[(size_t)row * 512 + k] = __float2bfloat16(W[(size_t)r * 1024 + k]);
  whbt[(size_t)row * 512 + k] = __float2bfloat16(W[(size_t)r * 1024 + 512 + k]);
  if (k == 0) bias[row] = B[r];
  if (idx < 2 * BATCH * HDIM) hbuf32[idx] = 0u;   // h=0 (bf16 0), tag=0 (=step 0)
}

// ---------------- convert x to bf16, 8 elems/thread
__global__ __launch_bounds__(256) void k_convx(const float* __restrict__ x,
                                               __hip_bfloat16* __restrict__ xbf)
{
  int idx = blockIdx.x * 256 + threadIdx.x;    // 8192 blocks
  const float4* p = (const float4*)x + (size_t)idx * 2;
  float4 a = p[0], b = p[1];
  short8 o;
  o[0]=bfb(a.x); o[1]=bfb(a.y); o[2]=bfb(a.z); o[3]=bfb(a.w);
  o[4]=bfb(b.x); o[5]=bfb(b.y); o[6]=bfb(b.z); o[7]=bfb(b.w);
  *(short8*)((short*)xbf + (size_t)idx * 8) = o;
}

// ---------------- phase 1 GEMM: [32768,512] x [512 -> 2048] (B^T layout), +bias
// Output re-laid: xproj[t][j][row][g][c]  (t=512, j=32 colgroups, row=64, g=4, c=16)
__global__ __launch_bounds__(256) void k_xproj(
    const __hip_bfloat16* __restrict__ xbf,   // [32768][512]
    const __hip_bfloat16* __restrict__ wxbt,  // [2048][512]
    const float* __restrict__ bias,           // [2048]
    __hip_bfloat16* __restrict__ xproj)       // [512][32][64][4][16]
{
  __shared__ __align__(16) short aT[128 * 64];
  __shared__ __align__(16) short bT[128 * 64];
  const int tid = threadIdx.x, lane = tid & 63, wave = tid >> 6;
  const int m0 = blockIdx.y * 128, n0 = blockIdx.x * 128;
  const int wr = wave >> 1, wc = wave & 1;

  f32x4 acc[4][4] = {};

  for (int s = 0; s < 8; ++s) {               // K=512, BK=64
    __syncthreads();
    const int kbyte = s * 128;
#pragma unroll
    for (int it = 0; it < 4; ++it) {
      int flat = it * 256 + tid;
      int row = flat >> 3, gr = flat & 7;
      int sgr = gr ^ (row & 7);
      const char* ga = (const char*)xbf  + (size_t)(m0 + row) * 1024 + kbyte + sgr * 16;
      const char* gb = (const char*)wxbt + (size_t)(n0 + row) * 1024 + kbyte + sgr * 16;
      gload_lds16(ga, (char*)aT + (it * 256 + wave * 64) * 16);
      gload_lds16(gb, (char*)bT + (it * 256 + wave * 64) * 16);
    }
    __syncthreads();
#pragma unroll
    for (int kk2 = 0; kk2 < 2; ++kk2) {
      short8 af[4], bfr[4];
#pragma unroll
      for (int mt = 0; mt < 4; ++mt) {
        int r = wr * 64 + mt * 16 + (lane & 15);
        int g = (kk2 * 4 + (lane >> 4)) ^ (r & 7);
        af[mt] = *(const short8*)((const char*)aT + r * 128 + g * 16);
      }
#pragma unroll
      for (int nt = 0; nt < 4; ++nt) {
        int r = wc * 64 + nt * 16 + (lane & 15);
        int g = (kk2 * 4 + (lane >> 4)) ^ (r & 7);
        bfr[nt] = *(const short8*)((const char*)bT + r * 128 + g * 16);
      }
#pragma unroll
      for (int mt = 0; mt < 4; ++mt)
#pragma unroll
        for (int nt = 0; nt < 4; ++nt)
          acc[mt][nt] = __builtin_amdgcn_mfma_f32_16x16x32_bf16(af[mt], bfr[nt], acc[mt][nt], 0, 0, 0);
    }
  }
  // epilogue: + bias, store bf16 into re-laid layout. C: col=lane&15, row=(lane>>4)*4+i
#pragma unroll
  for (int nt = 0; nt < 4; ++nt) {
    int n = n0 + wc * 64 + nt * 16 + (lane & 15);
    float bv = bias[n];
    int j2 = (n >> 4) & 31, g2 = n >> 9, c2 = n & 15;
#pragma unroll
    for (int mt = 0; mt < 4; ++mt)
#pragma unroll
      for (int i = 0; i < 4; ++i) {
        int m = m0 + wr * 64 + mt * 16 + (lane >> 4) * 4 + i;
        int tt = m >> 6, rr = m & 63;
        xproj[(((size_t)tt * 32 + j2) * 64 + rr) * 64 + g2 * 16 + c2] =
            __float2bfloat16(acc[mt][nt][i] + bv);
      }
  }
}

// ---------------- phase 2: 128 independent waves (64-thread WGs).
// Wave bid: j = bid>>2 owns h-cols [j*16,j*16+16); w = bid&3 owns batch rows
// [w*16,w*16+16). hbuf32[2][64][512]: word = bf16(h) | tag<<16. Consumer at step
// t reads buf[t&1] expecting tag==t everywhere; producer at step t writes tag
// t+1 into buf[(t+1)&1]. Tags in buf[t&1] during step-t poll are in {t,t-2,0}
// (peers cannot pass step t before this wave publishes t+1), all < t except
// fresh -> AND-reduction high half == t iff every word fresh.
__global__ __launch_bounds__(64, 1) void k_recur(
    const __hip_bfloat16* __restrict__ xproj, // [512][32][64][4][16]
    const __hip_bfloat16* __restrict__ whbt,  // [2048][512]
    unsigned* __restrict__ hbuf32,            // [2][64][512] tagged words
    float* __restrict__ out)                  // outputs | hx | cx
{
  const int lane = threadIdx.x;
  const int bid  = blockIdx.x;                 // 0..127
  const int j = bid >> 2, w = bid & 3;
  const int hc0 = j * 16, col = lane & 15, q = lane >> 4, mrow = q * 4;

  float c_state[4] = {0.f, 0.f, 0.f, 0.f};
  float* out_hx = out + (size_t)T_STEPS * BATCH * HDIM;
  float* out_cx = out_hx + BATCH * HDIM;

  // invariant base for this wave's Wh slice: B[k][c]=whbt[g*512+hc0+c][k],
  // per lane c=lane&15, k=kk*32+q*8+0..7
  const char* wbase = (const char*)whbt + ((size_t)(hc0 + col)) * 1024 + q * 16;
  // per-lane h word base (element r*512 + q*8), r = w*16 + (lane&15)
  const char* hbl = (const char*)hbuf32 +
                    ((size_t)(w * 16 + (lane & 15)) * 512 + q * 8) * 4;

  for (int t = 0; t < T_STEPS; ++t) {
    const int cur = t & 1;
    // ---- Wh slice loads: plain, L1-hot, pinned pre-poll by "memory" clobbers
    short8 bw[16][4];
#pragma unroll
    for (int kk = 0; kk < 16; ++kk)
#pragma unroll
      for (int gg = 0; gg < 4; ++gg)
        bw[kk][gg] = *(const short8*)(wbase + (size_t)gg * 524288 + (size_t)kk * 64);

    // ---- xp loads, pre-poll (drained by the poll's vmcnt(0))
    const char* xpb = (const char*)xproj +
        (((size_t)t * 32 + j) * 4096 + (size_t)(w * 16 + mrow) * 64 + col) * 2;
    unsigned xpu[4][4];
#pragma unroll
    for (int g = 0; g < 4; ++g)
#pragma unroll
      for (int i = 0; i < 4; ++i) {
        const void* p = xpb + i * 128 + g * 32;
        asm volatile("global_load_ushort %0, %1, off"
                     : "=v"(xpu[g][i]) : "v"(p) : "memory");
      }

    // ---- poll-and-load h^t: load the full A-slice, validate ALL tags.
    const char* hb = hbl + (size_t)cur * (BATCH * HDIM * 4);
    int4v raw[32];
    unsigned andv;
    do {
#pragma unroll
      for (int kk = 0; kk < 16; ++kk) {
        const void* p0 = hb + (size_t)kk * 128;        // kk*32 words * 4B
        const void* p1 = hb + (size_t)kk * 128 + 16;
        asm volatile("global_load_dwordx4 %0, %1, off sc0 sc1"
                     : "=v"(raw[2 * kk]) : "v"(p0) : "memory");
        asm volatile("global_load_dwordx4 %0, %1, off sc0 sc1"
                     : "=v"(raw[2 * kk + 1]) : "v"(p1) : "memory");
      }
      asm volatile("s_waitcnt vmcnt(0)" ::: "memory");
      __builtin_amdgcn_sched_barrier(0);   // rule #18: no check before the drain
      andv = 0xffffffffu;
#pragma unroll
      for (int ii = 0; ii < 32; ++ii)
        andv &= (unsigned)raw[ii][0] & (unsigned)raw[ii][1]
              & (unsigned)raw[ii][2] & (unsigned)raw[ii][3];
    } while ((andv >> 16) != (unsigned)t);   // per-lane divergent exit (R6-proven)
    __builtin_amdgcn_sched_barrier(0);

    // ---- unpack tagged words -> bf16 A fragments, MFMA
    f32x4 acc[4] = {};
#pragma unroll
    for (int kk = 0; kk < 16; ++kk) {
      int4v afw;
      afw[0] = (raw[2*kk][0]   & 0xffff) | (raw[2*kk][1]   << 16);
      afw[1] = (raw[2*kk][2]   & 0xffff) | (raw[2*kk][3]   << 16);
      afw[2] = (raw[2*kk+1][0] & 0xffff) | (raw[2*kk+1][1] << 16);
      afw[3] = (raw[2*kk+1][2] & 0xffff) | (raw[2*kk+1][3] << 16);
      short8 af = __builtin_bit_cast(short8, afw);
#pragma unroll
      for (int gg = 0; gg < 4; ++gg)
        acc[gg] = __builtin_amdgcn_mfma_f32_16x16x32_bf16(af, bw[kk][gg], acc[gg], 0, 0, 0);
    }

    // ---- epilogue: gates, state update (xpu drained by the poll's vmcnt(0))
    float hnv[4], cnv[4];
#pragma unroll
    for (int i = 0; i < 4; ++i) {
      float pf = acc[0][i] + bf2f(xpu[0][i]);
      float pi = acc[1][i] + bf2f(xpu[1][i]);
      float pg = acc[2][i] + bf2f(xpu[2][i]);
      float po = acc[3][i] + bf2f(xpu[3][i]);
      float fg = sigf(pf), ig = sigf(pi), gg2 = tanh_fast(pg), og = sigf(po);
      float cn = fg * c_state[i] + ig * gg2;
      c_state[i] = cn;
      cnv[i] = cn;
      hnv[i] = og * tanh_fast(cn);
    }
    // ---- tagged h stores, fire-and-forget (no drain, no flag)
    if (t < T_STEPS - 1) {
      char* hnxt = (char*)hbuf32 + (size_t)(cur ^ 1) * (BATCH * HDIM * 4) +
                   ((size_t)(w * 16 + mrow) * 512 + hc0 + col) * 4;
      unsigned tag = ((unsigned)(t + 1)) << 16;
#pragma unroll
      for (int i = 0; i < 4; ++i) {
        unsigned word = bfbits(hnv[i]) | tag;
        void* p = hnxt + (size_t)i * 2048;
        asm volatile("global_store_dword %0, %1, off sc0 sc1"
                     :: "v"(p), "v"(word) : "memory");
      }
    }
    // ---- out stores (plain, L2-cached; drained by next poll's vmcnt(0))
    float* outb = out + ((size_t)t * BATCH + w * 16 + mrow) * HDIM + hc0 + col;
#pragma unroll
    for (int i = 0; i < 4; ++i) outb[(size_t)i * HDIM] = hnv[i];
    if (t == T_STEPS - 1) {
#pragma unroll
      for (int i = 0; i < 4; ++i) {
        out_hx[(size_t)(w * 16 + mrow + i) * HDIM + hc0 + col] = hnv[i];
        out_cx[(size_t)(w * 16 + mrow + i) * HDIM + hc0 + col] = cnv[i];
      }
    }
  }
}

extern "C" void kernel_launch(void* const* d_in, const int* in_sizes, int n_in,
                              void* d_out, int out_size, void* d_ws, size_t ws_size,
                              hipStream_t stream) {
  const float* x   = (const float*)d_in[0];
  const float* Wf  = (const float*)d_in[1];
  const float* bf_ = (const float*)d_in[2];
  const float* Wi  = (const float*)d_in[3];
  const float* bi  = (const float*)d_in[4];
  const float* Wg  = (const float*)d_in[5];
  const float* bg  = (const float*)d_in[6];
  const float* Wo  = (const float*)d_in[7];
  const float* bo  = (const float*)d_in[8];

  char* ws = (char*)d_ws;
  __hip_bfloat16* xbf   = (__hip_bfloat16*)(ws);                 // 33,554,432 B
  __hip_bfloat16* wxbt  = (__hip_bfloat16*)(ws + 33554432);      //  2,097,152 B
  __hip_bfloat16* whbt  = (__hip_bfloat16*)(ws + 35651584);      //  2,097,152 B
  float*          bias  = (float*)         (ws + 37748736);      //      8,192 B
  __hip_bfloat16* xproj = (__hip_bfloat16*)(ws + 37756928);      // 134,217,728 B
  unsigned*       hbuf32= (unsigned*)      (ws + 171974656);     //    262,144 B

  k_prep <<<4096, 256, 0, stream>>>(Wf, bf_, Wi, bi, Wg, bg, Wo, bo,
                                    wxbt, whbt, bias, hbuf32);
  k_convx<<<8192, 256, 0, stream>>>(x, xbf);
  k_xproj<<<dim3(16, 256), 256, 0, stream>>>(xbf, wxbt, bias, xproj);
  k_recur<<<128, 64, 0, stream>>>(xproj, whbt, hbuf32, (float*)d_out);
}